// Round 5
// baseline (2673.486 us; speedup 1.0000x reference)
//
#include <hip/hip_runtime.h>
#include <hip/hip_bf16.h>

// Problem constants
#define BB 128
#define TT 1024
#define DD 3
#define HH 512
#define CC 3

#define NG 8      // batch groups
#define NCH 8     // h-chunks per group
#define MB 16     // batch rows per group
#define HC 64     // h columns per chunk

typedef __attribute__((ext_vector_type(8))) __bf16 bf16x8;
typedef __attribute__((ext_vector_type(4))) float f32x4;
typedef __attribute__((ext_vector_type(4))) unsigned u32x4;   // asm-safe 16B tuple

// Persistent RNN. 64 blocks x 256 threads (8 groups x 8 chunks of 64
// h-cols), ~158KB LDS -> 1 block/CU. ALL cross-block traffic via the MALL
// (sc0 sc1 stores+loads) -- the only transport proven coherent on this HW
// (R0/R2 passed; R3's plain-store/sc0-load XCD-local path leaked staleness).
//
// Protocol = R2's self-validating tagged transport: state word u32 =
// (bf16<<16) | step_tag16 in Rbuf[2][B][H]. Producers fire-and-forget;
// consumers bulk-load and validate EVERY word (retry until fresh). R5:
//  (a) 64 blocks instead of 128 -> half the MALL request pressure; each 16B
//      consumer granule = one producer dwordx4 (atomically fresh-or-stale).
//  (b) per-wave advisory HINT poll (8 dwords, one per producer chunk)
//      before the 32KB bulk load: bulk retries ~1/step instead of ~2.7.
//      Hint is timing-only; bulk per-word validation is the correctness
//      backstop. Spin caps turn any protocol failure into a wrong answer
//      with counters instead of a hang.
// (R4->R5: inline-asm 16B operands switched to ext_vector_type -- hipcc
//  rejects HIP uint4/float4 structs as asm INPUTS.)
__global__ __launch_bounds__(256, 1) void rnn_persist(
    const float* __restrict__ x,    // [B][T][D]
    const float* __restrict__ W,    // [H][H]
    const float* __restrict__ P,    // [H][D]
    const float* __restrict__ bv,   // [H]
    const float* __restrict__ Wz,   // [H][H]
    const float* __restrict__ Pz,   // [H][D]
    const float* __restrict__ bz,   // [H]
    float* __restrict__ hidden,     // [B][T][H] (inside d_out)
    unsigned* __restrict__ Rbuf,    // [2][B][H] u32 = (bf16<<16)|tag (d_ws)
    unsigned* __restrict__ ready)   // [64] clear-rendezvous (d_ws, zeroed)
{
    __shared__ __align__(16) __bf16 Wl[128][520];  // rows 0..63 Wz, 64..127 W (pitch 520)
    __shared__ __align__(16) __bf16 Ra[16][520];   // staged state S_t (bf16)
    __shared__ float pre[16][132];                 // MFMA out: [batch][col], 0..63 z, 64..127 cand

    const int tid = threadIdx.x;
    const int bid = blockIdx.x;
    const int g   = bid & 7;         // batch group
    const int ch  = bid >> 3;        // h chunk 0..7
    const int h0  = ch * HC;
    const int b0  = g * MB;

    // ---- one-time: weights -> LDS bf16 (128 rows x 512) ----
    for (int idx = tid; idx < 128 * 512; idx += 256) {
        int row = idx >> 9, col = idx & 511;
        float v = (row < 64) ? Wz[(h0 + row) * HH + col]
                             : W[(h0 + row - 64) * HH + col];
        Wl[row][col] = (__bf16)v;
    }

    const int lane = tid & 63;
    const int wv   = tid >> 6;       // wave -> output cols [wv*32, wv*32+32)
    const int frow = lane & 15;
    const int q    = lane >> 4;
    const int eb   = tid >> 4;       // elementwise batch row 0..15
    const int ehq  = tid & 15;       // elementwise h-quad 0..15
    const int hl   = ehq * 4;        // owns h0+hl .. h0+hl+3

    // per-thread small weights in registers (4 h columns, scalars: no
    // runtime-indexed arrays -> no scratch)
    const int hg0 = h0 + hl, hg1 = hg0 + 1, hg2 = hg0 + 2, hg3 = hg0 + 3;
    const float pz00 = Pz[hg0*3+0], pz01 = Pz[hg0*3+1], pz02 = Pz[hg0*3+2];
    const float pz10 = Pz[hg1*3+0], pz11 = Pz[hg1*3+1], pz12 = Pz[hg1*3+2];
    const float pz20 = Pz[hg2*3+0], pz21 = Pz[hg2*3+1], pz22 = Pz[hg2*3+2];
    const float pz30 = Pz[hg3*3+0], pz31 = Pz[hg3*3+1], pz32 = Pz[hg3*3+2];
    const float pv00 = (hg0 < HH/2) ? P[hg0*3+0] : 0.f;
    const float pv01 = (hg0 < HH/2) ? P[hg0*3+1] : 0.f;
    const float pv02 = (hg0 < HH/2) ? P[hg0*3+2] : 0.f;
    const float pv10 = (hg1 < HH/2) ? P[hg1*3+0] : 0.f;
    const float pv11 = (hg1 < HH/2) ? P[hg1*3+1] : 0.f;
    const float pv12 = (hg1 < HH/2) ? P[hg1*3+2] : 0.f;
    const float pv20 = (hg2 < HH/2) ? P[hg2*3+0] : 0.f;
    const float pv21 = (hg2 < HH/2) ? P[hg2*3+1] : 0.f;
    const float pv22 = (hg2 < HH/2) ? P[hg2*3+2] : 0.f;
    const float pv30 = (hg3 < HH/2) ? P[hg3*3+0] : 0.f;
    const float pv31 = (hg3 < HH/2) ? P[hg3*3+1] : 0.f;
    const float pv32 = (hg3 < HH/2) ? P[hg3*3+2] : 0.f;
    const float bzr0 = bz[hg0], bzr1 = bz[hg1], bzr2 = bz[hg2], bzr3 = bz[hg3];
    const float bvr0 = bv[hg0], bvr1 = bv[hg1], bvr2 = bv[hg2], bvr3 = bv[hg3];

    // ---- startup: sentinel-clear own slots in BOTH buffers, drain ----
    {
        u32x4 cl = {0xFFFFFFFFu, 0xFFFFFFFFu, 0xFFFFFFFFu, 0xFFFFFFFFu};
        unsigned* d0 = Rbuf + (size_t)(b0 + eb) * HH + h0 + hl;
        unsigned* d1 = d0 + BB * HH;
        asm volatile("global_store_dwordx4 %0, %2, off sc0 sc1\n\t"
                     "global_store_dwordx4 %1, %2, off sc0 sc1\n\t"
                     "s_waitcnt vmcnt(0)"
                     :: "v"(d0), "v"(d1), "v"(cl) : "memory");
    }
    __syncthreads();
    // ---- group rendezvous: all 8 members' clears acked (at MALL) before
    //      any publish (kills cross-replay stale-tag collisions) ----
    if (tid == 0)
        __hip_atomic_store(&ready[g * 8 + ch], 1u, __ATOMIC_RELAXED, __HIP_MEMORY_SCOPE_AGENT);
    if (tid < 8) {
        const unsigned* rp = &ready[g * 8 + tid];
        int spin = 0;
        while (__hip_atomic_load(rp, __ATOMIC_RELAXED, __HIP_MEMORY_SCOPE_AGENT) == 0u) {
            if (++spin > (1 << 22)) break;        // hang-proofing
        }
    }
    __syncthreads();

    // preload B fragments (weights) into registers: 2 n-tiles x 16 ks
    bf16x8 Bfrag0[16], Bfrag1[16];
    #pragma unroll
    for (int ks = 0; ks < 16; ks++) {
        Bfrag0[ks] = *(const bf16x8*)&Wl[wv * 32 +      frow][ks * 32 + q * 8];
        Bfrag1[ks] = *(const bf16x8*)&Wl[wv * 32 + 16 + frow][ks * 32 + q * 8];
    }

    float rs0 = 0.f, rs1 = 0.f, rs2 = 0.f, rs3 = 0.f;  // f32 state in regs
    const float* xptr = x + (size_t)(b0 + eb) * TT * DD;

    // staging geometry: thread loads 8 x 16B granules, rows 2i + r0, cols
    // [c4*4, c4*4+4). Each granule = one producer thread's dwordx4.
    const int c4 = tid & 127;
    const int r0 = tid >> 7;
    char* rb = (char*)&Ra[0][0] + r0 * 1040 + c4 * 8;  // LDS dest (row pitch 1040B)

    #define BAD4(G) ((((G).x ^ w16) | ((G).y ^ w16) | ((G).z ^ w16) | ((G).w ^ w16)) & 0xFFFFu)

    for (int t = 0; t < TT; t++) {
        float x0 = xptr[0], x1 = xptr[1], x2 = xptr[2];   // overlaps the wait
        xptr += DD;

        float mz0, mz1, mz2, mz3, mc0, mc1, mc2, mc3;
        if (t > 0) {
            const unsigned w16 = (unsigned)t;             // S_t carries tag t
            // ---- advisory hint poll (per-wave, lanes 0..7: one tagged word
            //      per producer chunk; 32B/spin instead of 32KB/spin) ----
            {
                const unsigned* hp = Rbuf + (size_t)(t & 1) * (BB * HH)
                                   + (size_t)b0 * HH + (lane & 7) * HC;
                const bool act = (lane < 8);
                int spin = 0;
                for (;;) {
                    unsigned v = w16;
                    if (act)
                        asm volatile("global_load_dword %0, %1, off sc0 sc1\n\t"
                                     "s_waitcnt vmcnt(0)"
                                     : "=&v"(v) : "v"(hp) : "memory");
                    if (__all((int)((v & 0xFFFFu) == w16))) break;
                    if (++spin > (1 << 14)) break;        // hang-proofing
                }
            }
            // ---- bulk load + authoritative per-word validation ----
            const unsigned* bse = Rbuf + (size_t)(t & 1) * (BB * HH)
                                + (size_t)(b0 + r0) * HH + (c4 << 2);
            const unsigned* q0 = bse;
            const unsigned* q1 = bse + 1024;   // +2 rows
            const unsigned* q2 = bse + 2048;
            const unsigned* q3 = bse + 3072;
            const unsigned* q4 = bse + 4096;
            const unsigned* q5 = bse + 5120;
            const unsigned* q6 = bse + 6144;
            const unsigned* q7 = bse + 7168;
            u32x4 G0, G1, G2, G3, G4, G5, G6, G7;
            int spin = 0;
            for (;;) {
                asm volatile(
                    "global_load_dwordx4 %0, %8, off sc0 sc1\n\t"
                    "global_load_dwordx4 %1, %9, off sc0 sc1\n\t"
                    "global_load_dwordx4 %2, %10, off sc0 sc1\n\t"
                    "global_load_dwordx4 %3, %11, off sc0 sc1\n\t"
                    "global_load_dwordx4 %4, %12, off sc0 sc1\n\t"
                    "global_load_dwordx4 %5, %13, off sc0 sc1\n\t"
                    "global_load_dwordx4 %6, %14, off sc0 sc1\n\t"
                    "global_load_dwordx4 %7, %15, off sc0 sc1\n\t"
                    "s_waitcnt vmcnt(0)"
                    : "=&v"(G0), "=&v"(G1), "=&v"(G2), "=&v"(G3),
                      "=&v"(G4), "=&v"(G5), "=&v"(G6), "=&v"(G7)
                    : "v"(q0), "v"(q1), "v"(q2), "v"(q3),
                      "v"(q4), "v"(q5), "v"(q6), "v"(q7)
                    : "memory");
                unsigned bad = BAD4(G0) | BAD4(G1) | BAD4(G2) | BAD4(G3)
                             | BAD4(G4) | BAD4(G5) | BAD4(G6) | BAD4(G7);
                if (bad == 0u) break;
                if (++spin > (1 << 12)) break;            // hang-proofing
            }
            // strip tags, pack bf16 pairs, stage to LDS (row = 2i + r0)
            { uint2 o; o.x=(G0.x>>16)|(G0.y&0xFFFF0000u); o.y=(G0.z>>16)|(G0.w&0xFFFF0000u);
              *(uint2*)(rb + 0*2080) = o; }
            { uint2 o; o.x=(G1.x>>16)|(G1.y&0xFFFF0000u); o.y=(G1.z>>16)|(G1.w&0xFFFF0000u);
              *(uint2*)(rb + 1*2080) = o; }
            { uint2 o; o.x=(G2.x>>16)|(G2.y&0xFFFF0000u); o.y=(G2.z>>16)|(G2.w&0xFFFF0000u);
              *(uint2*)(rb + 2*2080) = o; }
            { uint2 o; o.x=(G3.x>>16)|(G3.y&0xFFFF0000u); o.y=(G3.z>>16)|(G3.w&0xFFFF0000u);
              *(uint2*)(rb + 3*2080) = o; }
            { uint2 o; o.x=(G4.x>>16)|(G4.y&0xFFFF0000u); o.y=(G4.z>>16)|(G4.w&0xFFFF0000u);
              *(uint2*)(rb + 4*2080) = o; }
            { uint2 o; o.x=(G5.x>>16)|(G5.y&0xFFFF0000u); o.y=(G5.z>>16)|(G5.w&0xFFFF0000u);
              *(uint2*)(rb + 5*2080) = o; }
            { uint2 o; o.x=(G6.x>>16)|(G6.y&0xFFFF0000u); o.y=(G6.z>>16)|(G6.w&0xFFFF0000u);
              *(uint2*)(rb + 6*2080) = o; }
            { uint2 o; o.x=(G7.x>>16)|(G7.y&0xFFFF0000u); o.y=(G7.z>>16)|(G7.w&0xFFFF0000u);
              *(uint2*)(rb + 7*2080) = o; }
            __syncthreads();   // barrier 1: Ra staged

            // MFMA: D[m][n] = sum_k S[m][k] * Wl[n][k]; 2 n-tiles per wave
            f32x4 acc0 = {0.f, 0.f, 0.f, 0.f};
            f32x4 acc1 = {0.f, 0.f, 0.f, 0.f};
            #pragma unroll
            for (int ks = 0; ks < 16; ks++) {
                bf16x8 af = *(const bf16x8*)&Ra[frow][ks * 32 + q * 8];
                acc0 = __builtin_amdgcn_mfma_f32_16x16x32_bf16(af, Bfrag0[ks], acc0, 0, 0, 0);
                acc1 = __builtin_amdgcn_mfma_f32_16x16x32_bf16(af, Bfrag1[ks], acc1, 0, 0, 0);
            }
            #pragma unroll
            for (int r = 0; r < 4; r++) {
                pre[q * 4 + r][wv * 32 +      frow] = acc0[r];  // row=m, col=n
                pre[q * 4 + r][wv * 32 + 16 + frow] = acc1[r];
            }
            __syncthreads();   // barrier 2: pre ready

            mz0 = pre[eb][hl + 0];      mz1 = pre[eb][hl + 1];
            mz2 = pre[eb][hl + 2];      mz3 = pre[eb][hl + 3];
            mc0 = pre[eb][64 + hl + 0]; mc1 = pre[eb][64 + hl + 1];
            mc2 = pre[eb][64 + hl + 2]; mc3 = pre[eb][64 + hl + 3];
        } else {
            // S_0 = 0 -> matmul contribution is exactly zero; no staging
            mz0 = mz1 = mz2 = mz3 = 0.f;
            mc0 = mc1 = mc2 = mc3 = 0.f;
        }

        // gates + state update (state in registers)
        float pzq0 = mz0 + x0*pz00 + x1*pz01 + x2*pz02 + bzr0;
        float pzq1 = mz1 + x0*pz10 + x1*pz11 + x2*pz12 + bzr1;
        float pzq2 = mz2 + x0*pz20 + x1*pz21 + x2*pz22 + bzr2;
        float pzq3 = mz3 + x0*pz30 + x1*pz31 + x2*pz32 + bzr3;
        float pvq0 = mc0 + x0*pv00 + x1*pv01 + x2*pv02 + bvr0;
        float pvq1 = mc1 + x0*pv10 + x1*pv11 + x2*pv12 + bvr1;
        float pvq2 = mc2 + x0*pv20 + x1*pv21 + x2*pv22 + bvr2;
        float pvq3 = mc3 + x0*pv30 + x1*pv31 + x2*pv32 + bvr3;
        float z0 = 1.f / (1.f + __expf(-pzq0));
        float z1 = 1.f / (1.f + __expf(-pzq1));
        float z2 = 1.f / (1.f + __expf(-pzq2));
        float z3 = 1.f / (1.f + __expf(-pzq3));
        float c0 = 1.f / (1.f + __expf(-pvq0));
        float c1 = 1.f / (1.f + __expf(-pvq1));
        float c2 = 1.f / (1.f + __expf(-pvq2));
        float c3 = 1.f / (1.f + __expf(-pvq3));
        rs0 = (1.f - z0) * rs0 + z0 * c0;
        rs1 = (1.f - z1) * rs1 + z1 * c1;
        rs2 = (1.f - z2) * rs2 + z2 * c2;
        rs3 = (1.f - z3) * rs3 + z3 * c3;

        // publish S_{t+1} as 4 tagged u32 in ONE dwordx4: fire-and-forget
        // (tag rides in the data; consumers self-validate). S_1024 never read.
        if (t < TT - 1) {
            unsigned tagv = (unsigned)(t + 1);
            union { __bf16 h; unsigned short u; } a0, a1, a2, a3;
            a0.h = (__bf16)rs0; a1.h = (__bf16)rs1;
            a2.h = (__bf16)rs2; a3.h = (__bf16)rs3;
            u32x4 d = { ((unsigned)a0.u << 16) | tagv,
                        ((unsigned)a1.u << 16) | tagv,
                        ((unsigned)a2.u << 16) | tagv,
                        ((unsigned)a3.u << 16) | tagv };
            unsigned* dst = Rbuf + (size_t)((t + 1) & 1) * (BB * HH)
                          + (size_t)(b0 + eb) * HH + h0 + hl;
            asm volatile("global_store_dwordx4 %0, %1, off sc0 sc1"
                         :: "v"(dst), "v"(d) : "memory");
        }
        // hidden output (f32 exact state): fire-and-forget; drained by the
        // next iteration's bulk vmcnt(0), overlapped with the data wait
        f32x4 hv = {rs0, rs1, rs2, rs3};
        float* hid = &hidden[((size_t)(b0 + eb) * TT + t) * HH + h0 + hl];
        asm volatile("global_store_dwordx4 %0, %1, off"
                     :: "v"(hid), "v"(hv) : "memory");
        // no end-of-iteration barrier: barrier 1 of the next step protects Ra
    }
    #undef BAD4
}

// out[b][t][c] = hidden[b][t][:] . fc_W[c][:] + fc_b[c]; latency-hidden via
// 2-deep row prefetch, grid 1024. (Unchanged — re-examine once the RNN
// shrinks and this shows up in the top-5 counters.)
__global__ __launch_bounds__(256) void fc_kernel(
    const float* __restrict__ hidden, const float* __restrict__ fcW,
    const float* __restrict__ fcb, float* __restrict__ out)
{
    const int lane = threadIdx.x & 63;
    const int wid  = (blockIdx.x * blockDim.x + threadIdx.x) >> 6;
    const int nw   = (gridDim.x * blockDim.x) >> 6;
    const int NR   = BB * TT;

    float w0[8], w1[8], w2[8];
    #pragma unroll
    for (int j = 0; j < 8; j++) {
        w0[j] = fcW[0 * HH + lane * 8 + j];
        w1[j] = fcW[1 * HH + lane * 8 + j];
        w2[j] = fcW[2 * HH + lane * 8 + j];
    }
    const float c0 = fcb[0], c1 = fcb[1], c2 = fcb[2];

    int row = wid;
    float4 va, vb;
    if (row < NR) {
        const float* hr = hidden + (size_t)row * HH + lane * 8;
        va = *(const float4*)hr;
        vb = *(const float4*)(hr + 4);
    }
    while (row < NR) {
        int nrow = row + nw;
        float4 na, nb;
        if (nrow < NR) {
            const float* hr = hidden + (size_t)nrow * HH + lane * 8;
            na = *(const float4*)hr;
            nb = *(const float4*)(hr + 4);
        }
        float s0 = va.x*w0[0] + va.y*w0[1] + va.z*w0[2] + va.w*w0[3]
                 + vb.x*w0[4] + vb.y*w0[5] + vb.z*w0[6] + vb.w*w0[7];
        float s1 = va.x*w1[0] + va.y*w1[1] + va.z*w1[2] + va.w*w1[3]
                 + vb.x*w1[4] + vb.y*w1[5] + vb.z*w1[6] + vb.w*w1[7];
        float s2 = va.x*w2[0] + va.y*w2[1] + va.z*w2[2] + va.w*w2[3]
                 + vb.x*w2[4] + vb.y*w2[5] + vb.z*w2[6] + vb.w*w2[7];
        #pragma unroll
        for (int off = 1; off < 64; off <<= 1) {
            s0 += __shfl_xor(s0, off);
            s1 += __shfl_xor(s1, off);
            s2 += __shfl_xor(s2, off);
        }
        if (lane == 0) {
            float* o = out + (size_t)row * CC;
            o[0] = s0 + c0; o[1] = s1 + c1; o[2] = s2 + c2;
        }
        row = nrow; va = na; vb = nb;
    }
}

extern "C" void kernel_launch(void* const* d_in, const int* in_sizes, int n_in,
                              void* d_out, int out_size, void* d_ws, size_t ws_size,
                              hipStream_t stream) {
    (void)in_sizes; (void)n_in; (void)out_size; (void)ws_size;
    const float* x   = (const float*)d_in[0];
    const float* W   = (const float*)d_in[1];
    const float* P   = (const float*)d_in[2];
    const float* bv  = (const float*)d_in[3];
    const float* Wz  = (const float*)d_in[4];
    const float* Pz  = (const float*)d_in[5];
    const float* bz  = (const float*)d_in[6];
    const float* fcW = (const float*)d_in[7];
    const float* fcb = (const float*)d_in[8];

    float* out    = (float*)d_out;
    float* hidden = out + (size_t)BB * TT * CC;

    unsigned* ready = (unsigned*)d_ws;                        // [0,256B): rendezvous
    unsigned* Rbuf  = (unsigned*)((char*)d_ws + 4096);        // 2*128*512 u32 = 512KB

    (void)hipMemsetAsync(d_ws, 0, 4096, stream);
    hipLaunchKernelGGL(rnn_persist, dim3(NG * NCH), dim3(256), 0, stream,
                       x, W, P, bv, Wz, Pz, bz, hidden, Rbuf, ready);
    hipLaunchKernelGGL(fc_kernel, dim3(1024), dim3(256), 0, stream,
                       hidden, fcW, fcb, out);
}

// Round 6
// 2384.791 us; speedup vs baseline: 1.1211x; 1.1211x over previous
//
#include <hip/hip_runtime.h>
#include <hip/hip_bf16.h>

// Problem constants
#define BB 128
#define TT 1024
#define DD 3
#define HH 512
#define CC 3

#define NG 8      // batch groups
#define NCH 16    // h-chunks per group
#define MB 16     // batch rows per group
#define HC 32     // h columns per chunk

typedef __attribute__((ext_vector_type(8))) __bf16 bf16x8;
typedef __attribute__((ext_vector_type(4))) float f32x4;
typedef __attribute__((ext_vector_type(4))) unsigned u32x4;   // asm-safe 16B tuple

// Persistent RNN. 128 blocks x 256 threads, ~87KB LDS -> 1 block/CU, all
// co-resident. R6 = R2's proven self-validating tagged transport with ONE
// change: a 16B PROBE spin in front of the 32KB bulk load.
//
// Protocol: state word u32 = (bf16<<16) | step_tag16 in Rbuf[2][B][H].
// Producers fire-and-forget (no drain, no tag array, no end barrier).
// Consumers: (1) spin on a single 16B granule -- the one written by the
// producer group's LAST wave (rows 14/15), so probe-fresh ~implies all
// fresh -- at 16B/thread/spin (4KB/block) instead of R2's 32KB/spin,
// which saturated MALL bandwidth during the wait window (R2 FETCH 167MB,
// flat perf; R5's hint poll fixed traffic but added a serialized RT);
// (2) then ONE 8-granule bulk load with per-word tag validation (expected
// single iteration; capped retry as the correctness backstop). Spin caps
// turn any protocol failure into a wrong answer with counters, not a hang.
__global__ __launch_bounds__(256, 1) void rnn_persist(
    const float* __restrict__ x,    // [B][T][D]
    const float* __restrict__ W,    // [H][H]
    const float* __restrict__ P,    // [H][D]
    const float* __restrict__ bv,   // [H]
    const float* __restrict__ Wz,   // [H][H]
    const float* __restrict__ Pz,   // [H][D]
    const float* __restrict__ bz,   // [H]
    float* __restrict__ hidden,     // [B][T][H] (inside d_out)
    unsigned* __restrict__ Rbuf,    // [2][B][H] u32 = (bf16<<16)|tag (d_ws)
    unsigned* __restrict__ ready)   // [128] clear-rendezvous (d_ws, zeroed)
{
    __shared__ __align__(16) __bf16 Wl[64][520];  // rows 0..31 Wz, 32..63 W (pitch 520)
    __shared__ __align__(16) __bf16 Ra[16][520];  // staged state S_t (bf16)
    __shared__ float pre[16][68];                 // MFMA out: [batch][col], 0..31 z, 32..63 cand

    const int tid = threadIdx.x;
    const int bid = blockIdx.x;
    const int g   = bid & 7;         // batch group
    const int ch  = bid >> 3;        // h chunk 0..15
    const int h0  = ch * HC;
    const int b0  = g * MB;

    // ---- one-time: weights -> LDS bf16 ----
    for (int idx = tid; idx < 64 * 512; idx += 256) {
        int row = idx >> 9, col = idx & 511;
        float v = (row < 32) ? Wz[(h0 + row) * HH + col]
                             : W[(h0 + row - 32) * HH + col];
        Wl[row][col] = (__bf16)v;
    }

    const int lane = tid & 63;
    const int wv   = tid >> 6;       // wave -> output cols [wv*16, wv*16+16)
    const int frow = lane & 15;
    const int q    = lane >> 4;
    const int eb   = tid >> 4;       // elementwise batch row 0..15
    const int ehp  = tid & 15;       // elementwise h-pair 0..15

    // per-thread small weights in registers (cols hl0, hl1 of this chunk)
    const int hl0 = 2 * ehp, hl1 = hl0 + 1;
    const int hg0 = h0 + hl0, hg1 = h0 + hl1;
    const float pzw00 = Pz[hg0*3+0], pzw01 = Pz[hg0*3+1], pzw02 = Pz[hg0*3+2];
    const float pzw10 = Pz[hg1*3+0], pzw11 = Pz[hg1*3+1], pzw12 = Pz[hg1*3+2];
    const float pvw00 = (hg0 < HH/2) ? P[hg0*3+0] : 0.f;
    const float pvw01 = (hg0 < HH/2) ? P[hg0*3+1] : 0.f;
    const float pvw02 = (hg0 < HH/2) ? P[hg0*3+2] : 0.f;
    const float pvw10 = (hg1 < HH/2) ? P[hg1*3+0] : 0.f;
    const float pvw11 = (hg1 < HH/2) ? P[hg1*3+1] : 0.f;
    const float pvw12 = (hg1 < HH/2) ? P[hg1*3+2] : 0.f;
    const float bzr0 = bz[hg0], bzr1 = bz[hg1];
    const float bvr0 = bv[hg0], bvr1 = bv[hg1];

    // ---- startup: sentinel-clear own slots in BOTH buffers, drain ----
    {
        uint2 cl; cl.x = 0xFFFFFFFFu; cl.y = 0xFFFFFFFFu;
        unsigned* d0 = Rbuf + (size_t)(b0 + eb) * HH + h0 + hl0;
        unsigned* d1 = d0 + BB * HH;
        asm volatile("global_store_dwordx2 %0, %2, off sc0 sc1\n\t"
                     "global_store_dwordx2 %1, %2, off sc0 sc1\n\t"
                     "s_waitcnt vmcnt(0)"
                     :: "v"(d0), "v"(d1), "v"(cl) : "memory");
    }
    __syncthreads();
    // ---- one-time group rendezvous: all clears acked before any publish ----
    if (tid == 0)
        __hip_atomic_store(&ready[bid], 1u, __ATOMIC_RELAXED, __HIP_MEMORY_SCOPE_AGENT);
    if (tid < 16) {
        const unsigned* rp = &ready[tid * 8 + g];   // group member bids = c*8+g
        int spin = 0;
        while (__hip_atomic_load(rp, __ATOMIC_RELAXED, __HIP_MEMORY_SCOPE_AGENT) == 0u) {
            if (++spin > (1 << 22)) break;          // hang-proofing
        }
    }
    __syncthreads();

    // preload B fragments (weights) into registers: 16 x bf16x8 = 64 VGPRs
    bf16x8 Bfrag[16];
    #pragma unroll
    for (int ks = 0; ks < 16; ks++)
        Bfrag[ks] = *(const bf16x8*)&Wl[wv * 16 + frow][ks * 32 + q * 8];

    float rs0 = 0.f, rs1 = 0.f;      // f32 state for (eb, hl0/hl1) lives in regs
    const float* xptr = x + (size_t)(b0 + eb) * TT * DD;

    // staging geometry: thread loads 8 x 16B granules, rows 2i + r0, cols
    // [c4*4, c4*4+4). All granules of one thread come from ONE producer chunk.
    const int c4 = tid & 127;
    const int r0 = tid >> 7;
    char* rb = (char*)&Ra[0][0] + r0 * 1040 + c4 * 8;  // LDS dest (row pitch 1040B)

    #define BAD4(G) ((((G).x ^ w16) | ((G).y ^ w16) | ((G).z ^ w16) | ((G).w ^ w16)) & 0xFFFFu)

    for (int t = 0; t < TT; t++) {
        float x0 = xptr[0], x1 = xptr[1], x2 = xptr[2];   // overlaps the wait
        xptr += DD;

        float mz0, mz1, mc0, mc1;
        if (t > 0) {
            const unsigned w16 = (unsigned)t;             // S_t carries tag t
            const unsigned* bse = Rbuf + (size_t)(t & 1) * (BB * HH)
                                + (size_t)(b0 + r0) * HH + (c4 << 2);
            const unsigned* q0 = bse;
            const unsigned* q1 = bse + 1024;   // +2 rows
            const unsigned* q2 = bse + 2048;
            const unsigned* q3 = bse + 3072;
            const unsigned* q4 = bse + 4096;
            const unsigned* q5 = bse + 5120;
            const unsigned* q6 = bse + 6144;
            const unsigned* q7 = bse + 7168;   // rows 14/15: producer's LAST wave

            // ---- PROBE: 16B spin on the last-wave granule (cheap wait) ----
            {
                u32x4 Gp;
                int spin = 0;
                for (;;) {
                    asm volatile("global_load_dwordx4 %0, %1, off sc0 sc1\n\t"
                                 "s_waitcnt vmcnt(0)"
                                 : "=&v"(Gp) : "v"(q7) : "memory");
                    if (BAD4(Gp) == 0u) break;
                    if (++spin > (1 << 14)) break;        // hang-proofing
                }
            }

            // ---- BULK: one validated 8-granule load (expected 1 iter) ----
            u32x4 G0, G1, G2, G3, G4, G5, G6, G7;
            int spin = 0;
            for (;;) {
                asm volatile(
                    "global_load_dwordx4 %0, %8, off sc0 sc1\n\t"
                    "global_load_dwordx4 %1, %9, off sc0 sc1\n\t"
                    "global_load_dwordx4 %2, %10, off sc0 sc1\n\t"
                    "global_load_dwordx4 %3, %11, off sc0 sc1\n\t"
                    "global_load_dwordx4 %4, %12, off sc0 sc1\n\t"
                    "global_load_dwordx4 %5, %13, off sc0 sc1\n\t"
                    "global_load_dwordx4 %6, %14, off sc0 sc1\n\t"
                    "global_load_dwordx4 %7, %15, off sc0 sc1\n\t"
                    "s_waitcnt vmcnt(0)"
                    : "=&v"(G0), "=&v"(G1), "=&v"(G2), "=&v"(G3),
                      "=&v"(G4), "=&v"(G5), "=&v"(G6), "=&v"(G7)
                    : "v"(q0), "v"(q1), "v"(q2), "v"(q3),
                      "v"(q4), "v"(q5), "v"(q6), "v"(q7)
                    : "memory");
                unsigned bad = BAD4(G0) | BAD4(G1) | BAD4(G2) | BAD4(G3)
                             | BAD4(G4) | BAD4(G5) | BAD4(G6) | BAD4(G7);
                if (bad == 0u) break;
                if (++spin > (1 << 12)) break;            // hang-proofing
            }
            // strip tags, pack bf16 pairs, stage to LDS (row = 2i + r0)
            { uint2 o; o.x=(G0.x>>16)|(G0.y&0xFFFF0000u); o.y=(G0.z>>16)|(G0.w&0xFFFF0000u);
              *(uint2*)(rb + 0*2080) = o; }
            { uint2 o; o.x=(G1.x>>16)|(G1.y&0xFFFF0000u); o.y=(G1.z>>16)|(G1.w&0xFFFF0000u);
              *(uint2*)(rb + 1*2080) = o; }
            { uint2 o; o.x=(G2.x>>16)|(G2.y&0xFFFF0000u); o.y=(G2.z>>16)|(G2.w&0xFFFF0000u);
              *(uint2*)(rb + 2*2080) = o; }
            { uint2 o; o.x=(G3.x>>16)|(G3.y&0xFFFF0000u); o.y=(G3.z>>16)|(G3.w&0xFFFF0000u);
              *(uint2*)(rb + 3*2080) = o; }
            { uint2 o; o.x=(G4.x>>16)|(G4.y&0xFFFF0000u); o.y=(G4.z>>16)|(G4.w&0xFFFF0000u);
              *(uint2*)(rb + 4*2080) = o; }
            { uint2 o; o.x=(G5.x>>16)|(G5.y&0xFFFF0000u); o.y=(G5.z>>16)|(G5.w&0xFFFF0000u);
              *(uint2*)(rb + 5*2080) = o; }
            { uint2 o; o.x=(G6.x>>16)|(G6.y&0xFFFF0000u); o.y=(G6.z>>16)|(G6.w&0xFFFF0000u);
              *(uint2*)(rb + 6*2080) = o; }
            { uint2 o; o.x=(G7.x>>16)|(G7.y&0xFFFF0000u); o.y=(G7.z>>16)|(G7.w&0xFFFF0000u);
              *(uint2*)(rb + 7*2080) = o; }
            __syncthreads();   // barrier 1: Ra staged

            // MFMA: D[m][n] = sum_k S[m][k] * Wl[n][k]; A from LDS, B from regs
            f32x4 acc = {0.f, 0.f, 0.f, 0.f};
            #pragma unroll
            for (int ks = 0; ks < 16; ks++) {
                bf16x8 af = *(const bf16x8*)&Ra[frow][ks * 32 + q * 8];
                acc = __builtin_amdgcn_mfma_f32_16x16x32_bf16(af, Bfrag[ks], acc, 0, 0, 0);
            }
            #pragma unroll
            for (int r = 0; r < 4; r++)
                pre[q * 4 + r][wv * 16 + frow] = acc[r];   // row=m (batch), col=n
            __syncthreads();   // barrier 2: pre ready

            mz0 = pre[eb][hl0];      mz1 = pre[eb][hl1];
            mc0 = pre[eb][32 + hl0]; mc1 = pre[eb][32 + hl1];
        } else {
            // S_0 = 0 -> matmul contribution is exactly zero; no staging
            mz0 = mz1 = mc0 = mc1 = 0.f;
        }

        // gates + state update (state in registers)
        float pz0 = mz0 + x0*pzw00 + x1*pzw01 + x2*pzw02 + bzr0;
        float pz1 = mz1 + x0*pzw10 + x1*pzw11 + x2*pzw12 + bzr1;
        float pv0 = mc0 + x0*pvw00 + x1*pvw01 + x2*pvw02 + bvr0;
        float pv1 = mc1 + x0*pvw10 + x1*pvw11 + x2*pvw12 + bvr1;
        float z0 = 1.f / (1.f + __expf(-pz0));
        float z1 = 1.f / (1.f + __expf(-pz1));
        float c0 = 1.f / (1.f + __expf(-pv0));
        float c1 = 1.f / (1.f + __expf(-pv1));
        rs0 = (1.f - z0) * rs0 + z0 * c0;
        rs1 = (1.f - z1) * rs1 + z1 * c1;

        // publish S_{t+1} as tagged u32 pair: FIRE AND FORGET (no drain; the
        // tag rides in the data, consumers self-validate). S_1024 never read.
        if (t < TT - 1) {
            unsigned tagv = (unsigned)(t + 1);
            union { __bf16 h; unsigned short u; } a0, a1;
            a0.h = (__bf16)rs0; a1.h = (__bf16)rs1;
            uint2 d; d.x = ((unsigned)a0.u << 16) | tagv;
                     d.y = ((unsigned)a1.u << 16) | tagv;
            unsigned* dst = Rbuf + (size_t)((t + 1) & 1) * (BB * HH)
                          + (size_t)(b0 + eb) * HH + h0 + hl0;
            asm volatile("global_store_dwordx2 %0, %1, off sc0 sc1"
                         :: "v"(dst), "v"(d) : "memory");
        }
        // hidden output (f32 exact state): fire-and-forget; drained by the
        // next iteration's bulk vmcnt(0), overlapped with the data wait
        union { float f[2]; uint2 u2; } hvu;
        hvu.f[0] = rs0; hvu.f[1] = rs1;
        float* hid = &hidden[((size_t)(b0 + eb) * TT + t) * HH + h0 + hl0];
        asm volatile("global_store_dwordx2 %0, %1, off"
                     :: "v"(hid), "v"(hvu.u2) : "memory");
        // no end-of-iteration barrier: barrier 1 of the next step protects Ra
    }
    #undef BAD4
}

// out[b][t][c] = hidden[b][t][:] . fc_W[c][:] + fc_b[c]; latency-hidden via
// 2-deep row prefetch. R6: grid 1024 -> 2048 (exactly fills 8192-wave
// capacity; was ~1.0 TB/s = TLP-limited at 1024).
__global__ __launch_bounds__(256) void fc_kernel(
    const float* __restrict__ hidden, const float* __restrict__ fcW,
    const float* __restrict__ fcb, float* __restrict__ out)
{
    const int lane = threadIdx.x & 63;
    const int wid  = (blockIdx.x * blockDim.x + threadIdx.x) >> 6;
    const int nw   = (gridDim.x * blockDim.x) >> 6;
    const int NR   = BB * TT;

    float w0[8], w1[8], w2[8];
    #pragma unroll
    for (int j = 0; j < 8; j++) {
        w0[j] = fcW[0 * HH + lane * 8 + j];
        w1[j] = fcW[1 * HH + lane * 8 + j];
        w2[j] = fcW[2 * HH + lane * 8 + j];
    }
    const float c0 = fcb[0], c1 = fcb[1], c2 = fcb[2];

    int row = wid;
    float4 va, vb;
    if (row < NR) {
        const float* hr = hidden + (size_t)row * HH + lane * 8;
        va = *(const float4*)hr;
        vb = *(const float4*)(hr + 4);
    }
    while (row < NR) {
        int nrow = row + nw;
        float4 na, nb;
        if (nrow < NR) {
            const float* hr = hidden + (size_t)nrow * HH + lane * 8;
            na = *(const float4*)hr;
            nb = *(const float4*)(hr + 4);
        }
        float s0 = va.x*w0[0] + va.y*w0[1] + va.z*w0[2] + va.w*w0[3]
                 + vb.x*w0[4] + vb.y*w0[5] + vb.z*w0[6] + vb.w*w0[7];
        float s1 = va.x*w1[0] + va.y*w1[1] + va.z*w1[2] + va.w*w1[3]
                 + vb.x*w1[4] + vb.y*w1[5] + vb.z*w1[6] + vb.w*w1[7];
        float s2 = va.x*w2[0] + va.y*w2[1] + va.z*w2[2] + va.w*w2[3]
                 + vb.x*w2[4] + vb.y*w2[5] + vb.z*w2[6] + vb.w*w2[7];
        #pragma unroll
        for (int off = 1; off < 64; off <<= 1) {
            s0 += __shfl_xor(s0, off);
            s1 += __shfl_xor(s1, off);
            s2 += __shfl_xor(s2, off);
        }
        if (lane == 0) {
            float* o = out + (size_t)row * CC;
            o[0] = s0 + c0; o[1] = s1 + c1; o[2] = s2 + c2;
        }
        row = nrow; va = na; vb = nb;
    }
}

extern "C" void kernel_launch(void* const* d_in, const int* in_sizes, int n_in,
                              void* d_out, int out_size, void* d_ws, size_t ws_size,
                              hipStream_t stream) {
    (void)in_sizes; (void)n_in; (void)out_size; (void)ws_size;
    const float* x   = (const float*)d_in[0];
    const float* W   = (const float*)d_in[1];
    const float* P   = (const float*)d_in[2];
    const float* bv  = (const float*)d_in[3];
    const float* Wz  = (const float*)d_in[4];
    const float* Pz  = (const float*)d_in[5];
    const float* bz  = (const float*)d_in[6];
    const float* fcW = (const float*)d_in[7];
    const float* fcb = (const float*)d_in[8];

    float* out    = (float*)d_out;
    float* hidden = out + (size_t)BB * TT * CC;

    unsigned* ready = (unsigned*)d_ws;                        // [0,512B): rendezvous
    unsigned* Rbuf  = (unsigned*)((char*)d_ws + 4096);        // 2*128*512 u32 = 512KB

    (void)hipMemsetAsync(d_ws, 0, 4096, stream);
    hipLaunchKernelGGL(rnn_persist, dim3(NG * NCH), dim3(256), 0, stream,
                       x, W, P, bv, Wz, Pz, bz, hidden, Rbuf, ready);
    hipLaunchKernelGGL(fc_kernel, dim3(2048), dim3(256), 0, stream,
                       hidden, fcW, fcb, out);
}